// Round 7
// baseline (82.602 us; speedup 1.0000x reference)
//
#include <hip/hip_runtime.h>

typedef unsigned long long u64;

#define N_DET 4096
#define NW 64               // 4096 bits = 64 u64 words
#define IOU_TR 0.3f
#define SCORE_TR 0.1f
#define EPS 1e-9f

// ---------------------------------------------------------------------------
// ws layout:
//   rows    : 4096*8 f32  (sorted detection rows)         128 KB
//   soa     : 7*4096 f32  (lox,loy,loz,hix,hiy,hiz,vol)   112 KB
//   A       : 64 u64      (bit i = suppression row i nonempty)
//   counter : 1 u32 (+pad)(last-block-done counter)
//   Trm     : 4096*64 u64 row-major bitmatrix; only nonempty rows written.
// 2 dispatches: k_sort, then k_supscan (sup matrix + last-block tail does the
// serial greedy scan + gated output in the same dispatch).
// ---------------------------------------------------------------------------

__device__ __forceinline__ u64 rl64(u64 v, int l) {
    unsigned lo = __builtin_amdgcn_readlane((unsigned)v, l);
    unsigned hi = __builtin_amdgcn_readlane((unsigned)(v >> 32), l);
    return ((u64)hi << 32) | lo;
}

// K1: stable descending rank sort (16 rows/block, 16 threads/row) + zero A/ctr.
__global__ void __launch_bounds__(256) k_sort(const float* __restrict__ res,
                                              float* __restrict__ rows,
                                              float* __restrict__ soa,
                                              u64* __restrict__ A,
                                              unsigned* __restrict__ counter) {
    __shared__ float s[N_DET];
    int tid = threadIdx.x;
    if (blockIdx.x == 0) {
        if (tid < 64) A[tid] = 0ull;
        if (tid == 64) *counter = 0u;
    }
    for (int j = tid; j < N_DET; j += 256) s[j] = res[j * 8];
    __syncthreads();
    int r = tid >> 4, c = tid & 15;
    int gi = blockIdx.x * 16 + r;
    float sc = s[gi];
    int part = 0;
    int j0 = c * 256;
    for (int j = j0; j < j0 + 256; ++j) {
        float sj = s[j];
        part += (sj > sc) || (sj == sc && j < gi);
    }
    part += __shfl_xor(part, 1, 64);
    part += __shfl_xor(part, 2, 64);
    part += __shfl_xor(part, 4, 64);
    part += __shfl_xor(part, 8, 64);
    if (c == 0) {
        int rank = part;
        float4 a = *(const float4*)(res + gi * 8);
        float4 b = *(const float4*)(res + gi * 8 + 4);
        *(float4*)(rows + rank * 8)     = a;
        *(float4*)(rows + rank * 8 + 4) = b;
        // a = (score, class, cx, cy); b = (cz, dx, dy, dz)
        float cx = a.z, cy = a.w, cz = b.x, dx = b.y, dy = b.z, dz = b.w;
        soa[0 * N_DET + rank] = cx - dx * 0.5f;
        soa[1 * N_DET + rank] = cy - dy * 0.5f;
        soa[2 * N_DET + rank] = cz - dz * 0.5f;
        soa[3 * N_DET + rank] = cx + dx * 0.5f;
        soa[4 * N_DET + rank] = cy + dy * 0.5f;
        soa[5 * N_DET + rank] = cz + dz * 0.5f;
        soa[6 * N_DET + rank] = (dx * dy) * dz;   // np.prod order ((dx*dy)*dz)
    }
}

// K2: suppression rows (upper-triangle only, wave-uniform div-skip) + tail.
// Last-finishing block runs the serial greedy scan + gated output.

#define FIDX(V, GB) { V = (unsigned)s_nlist[(GB) + (lane & 15)]; }

#define IS1(V, P, S) { unsigned si_ = __builtin_amdgcn_readlane((V), (S)); \
    P##S = Trm[(size_t)si_ * NW + lane]; }

#define IS16(V, P) IS1(V,P,0) IS1(V,P,1) IS1(V,P,2) IS1(V,P,3)   \
    IS1(V,P,4) IS1(V,P,5) IS1(V,P,6) IS1(V,P,7)                  \
    IS1(V,P,8) IS1(V,P,9) IS1(V,P,10) IS1(V,P,11)                \
    IS1(V,P,12) IS1(V,P,13) IS1(V,P,14) IS1(V,P,15)

#define PR1(V, P, S) { unsigned si_ = __builtin_amdgcn_readlane((V), (S)); \
    u64 awd_ = rl64(act, (int)(si_ >> 6));                                 \
    u64 bit_ = (awd_ >> (si_ & 63u)) & 1ull;                               \
    u64 m_ = (0ull - bit_) & (0ull - (u64)(si_ != 4095u));                 \
    act &= ~(P##S & m_); }

#define PR16(V, P) PR1(V,P,0) PR1(V,P,1) PR1(V,P,2) PR1(V,P,3)   \
    PR1(V,P,4) PR1(V,P,5) PR1(V,P,6) PR1(V,P,7)                  \
    PR1(V,P,8) PR1(V,P,9) PR1(V,P,10) PR1(V,P,11)                \
    PR1(V,P,12) PR1(V,P,13) PR1(V,P,14) PR1(V,P,15)

__global__ void __launch_bounds__(256, 1)
k_supscan(const float* __restrict__ soa, u64* __restrict__ Trm,
          u64* __restrict__ A, const float* __restrict__ rows,
          float* __restrict__ out, unsigned* __restrict__ counter) {
    __shared__ u64 s_valid[NW];
    __shared__ u64 s_keep[NW];
    __shared__ unsigned short s_nlist[4224];
    __shared__ int s_last;
    const int tid = threadIdx.x;
    const int wv = tid >> 6;
    const int lane = tid & 63;

    // ---- sup phase: one wave per row i, words w >= i>>6 only ----
    {
        int i = blockIdx.x * 4 + wv;
        float ilox = soa[0 * N_DET + i], iloy = soa[1 * N_DET + i], iloz = soa[2 * N_DET + i];
        float ihix = soa[3 * N_DET + i], ihiy = soa[4 * N_DET + i], ihiz = soa[5 * N_DET + i];
        float ivol = soa[6 * N_DET + i];
        u64 rowword = 0, rowOr = 0;
        for (int w = (i >> 6); w < NW; ++w) {
            int j = w * 64 + lane;
            float lox = soa[0 * N_DET + j], loy = soa[1 * N_DET + j], loz = soa[2 * N_DET + j];
            float hix = soa[3 * N_DET + j], hiy = soa[4 * N_DET + j], hiz = soa[5 * N_DET + j];
            float fx = fminf(ihix, hix) - fmaxf(ilox, lox);
            float fy = fminf(ihiy, hiy) - fmaxf(iloy, loy);
            float fz = fminf(ihiz, hiz) - fmaxf(iloz, loz);
            u64 ov = __ballot(fx > 0.0f && fy > 0.0f && fz > 0.0f);
            u64 m = 0ull;
            if (ov) {                                 // wave-uniform; ~3% taken
                float vol = soa[6 * N_DET + j];
                float ix = fmaxf(fx, 0.0f), iy = fmaxf(fy, 0.0f), iz = fmaxf(fz, 0.0f);
                float inter = (ix * iy) * iz;         // ((x*y)*z) like np.prod
                float uni = ivol + vol - inter;       // (vol_i+vol_j)-inter
                float iou = inter / (uni + EPS);      // IEEE div
                m = __ballot(iou > IOU_TR && j > i);
            }
            rowOr |= m;
            rowword = (lane == w) ? m : rowword;
        }
        if (rowOr) {                                  // wave-uniform branch
            Trm[(size_t)i * NW + lane] = rowword;     // coalesced 512B store
            if (lane == 0) atomicOr(&A[i >> 6], 1ull << (i & 63));
        }
    }
    __syncthreads();
    if (tid == 0) {
        __threadfence();                              // release Trm/A stores
        unsigned old = atomicAdd(counter, 1u);
        s_last = (old == (unsigned)(gridDim.x - 1));
    }
    __syncthreads();
    if (!s_last) return;
    __threadfence();                                  // acquire all blocks' stores

    // ---- tail (last block only): valid ballots + sparse scan + output ----
    for (int w = wv * 16; w < wv * 16 + 16; ++w) {
        float scw = rows[(w * 64 + lane) * 8];
        u64 m = __ballot(scw >= SCORE_TR);
        if (lane == 0) s_valid[w] = m;
    }
    __syncthreads();

    if (wv == 0) {
        u64 act = s_valid[lane];
        u64 avA = A[lane];
        int pc = __popcll(avA);
        int inc = pc;
#pragma unroll
        for (int d = 1; d < 64; d <<= 1) {
            int t = __shfl_up(inc, d, 64);
            if (lane >= d) inc += t;
        }
        int exc = inc - pc;
        int nTotal = __shfl(inc, 63, 64);
        {   // emit this lane's nonempty-row indices (sorted globally)
            u64 m = avA; int o = exc;
            while (m) {
                int k = __builtin_ctzll(m); m &= m - 1;
                s_nlist[o++] = (unsigned short)(lane * 64 + k);
            }
        }
        int padded = (nTotal + 63) & ~63;
        for (int t = nTotal + lane; t < padded + 128; t += 64)
            s_nlist[t] = (unsigned short)4095;
        __threadfence_block();                 // wave-local LDS ordering

        if (padded > 0) {                      // padded is a multiple of 64
            u64 pa0,pa1,pa2,pa3,pa4,pa5,pa6,pa7,
                pa8,pa9,pa10,pa11,pa12,pa13,pa14,pa15;
            u64 pb0,pb1,pb2,pb3,pb4,pb5,pb6,pb7,
                pb8,pb9,pb10,pb11,pb12,pb13,pb14,pb15;
            unsigned iA0, iA1, iB0, iB1;
            FIDX(iA0, 0)  IS16(iA0, pa)
            FIDX(iB0, 16) IS16(iB0, pb)
            int g = 0;
            while (g < padded) {
                FIDX(iA1, g + 32)
                PR16(iA0, pa)                  // rows g..g+15
                IS16(iA1, pa)                  // issue g+32
                FIDX(iB1, g + 48)
                PR16(iB0, pb)                  // rows g+16..g+31
                IS16(iB1, pb)                  // issue g+48
                g += 32;
                if (g >= padded) break;
                FIDX(iA0, g + 32)
                PR16(iA1, pa)
                IS16(iA0, pa)
                FIDX(iB0, g + 48)
                PR16(iB1, pb)
                IS16(iB0, pb)
                g += 32;
            }
        }
        s_keep[lane] = act;                    // final act == keep mask
    }
    __syncthreads();

    // gated output: 256 threads x 16 rows, coalesced
    for (int n = 0; n < 16; ++n) {
        int i = n * 256 + tid;
        bool kp = (s_keep[i >> 6] >> (i & 63)) & 1ull;
        float4 a = kp ? ((const float4*)rows)[i * 2]     : make_float4(0.f, 0.f, 0.f, 0.f);
        float4 b = kp ? ((const float4*)rows)[i * 2 + 1] : make_float4(0.f, 0.f, 0.f, 0.f);
        ((float4*)out)[i * 2]     = a;
        ((float4*)out)[i * 2 + 1] = b;
    }
}

extern "C" void kernel_launch(void* const* d_in, const int* in_sizes, int n_in,
                              void* d_out, int out_size, void* d_ws, size_t ws_size,
                              hipStream_t stream) {
    const float* res = (const float*)d_in[0];
    float* out = (float*)d_out;

    float* rows = (float*)d_ws;                       // 32768 f32
    float* soa  = rows + N_DET * 8;                   // 28672 f32
    u64* A      = (u64*)(soa + 7 * N_DET);            // 64 u64
    unsigned* counter = (unsigned*)(A + NW);          // 1 u32 (+pad to 64B)
    u64* Trm    = A + NW + 8;                         // 4096*64 u64 (row-major)

    k_sort   <<<N_DET / 16, 256, 0, stream>>>(res, rows, soa, A, counter);
    k_supscan<<<N_DET / 4, 256, 0, stream>>>(soa, Trm, A, rows, out, counter);
}

// Round 8
// 59.379 us; speedup vs baseline: 1.3911x; 1.3911x over previous
//
#include <hip/hip_runtime.h>

typedef unsigned long long u64;

#define N_DET 4096
#define NW 64               // 4096 bits = 64 u64 words
#define IOU_TR 0.3f
#define SCORE_TR 0.1f
#define EPS 1e-9f

// ---------------------------------------------------------------------------
// ws layout:
//   rows : 4096*8 f32  (sorted detection rows)         128 KB
//   soa  : 7*4096 f32  (lox,loy,loz,hix,hiy,hiz,vol)   112 KB
//   A    : 64 u64      (bit i = suppression row i nonempty)
//   keep : 64 u64      (final keep mask)
//   Trm  : 4096*64 u64 row-major bitmatrix; only nonempty rows written.
// 4 dispatches (deliberately de-fused this round for per-phase rocprof
// attribution): k_sort, k_sup (upper-triangle), k_scan (1 block), k_out.
// ---------------------------------------------------------------------------

__device__ __forceinline__ u64 rl64(u64 v, int l) {
    unsigned lo = __builtin_amdgcn_readlane((unsigned)v, l);
    unsigned hi = __builtin_amdgcn_readlane((unsigned)(v >> 32), l);
    return ((u64)hi << 32) | lo;
}

// K1: stable descending rank sort (16 rows/block, 16 threads/row) + zero A.
__global__ void __launch_bounds__(256) k_sort(const float* __restrict__ res,
                                              float* __restrict__ rows,
                                              float* __restrict__ soa,
                                              u64* __restrict__ A) {
    __shared__ float s[N_DET];
    int tid = threadIdx.x;
    if (blockIdx.x == 0 && tid < 64) A[tid] = 0ull;
    for (int j = tid; j < N_DET; j += 256) s[j] = res[j * 8];
    __syncthreads();
    int r = tid >> 4, c = tid & 15;
    int gi = blockIdx.x * 16 + r;
    float sc = s[gi];
    int part = 0;
    int j0 = c * 256;
    for (int j = j0; j < j0 + 256; ++j) {
        float sj = s[j];
        part += (sj > sc) || (sj == sc && j < gi);
    }
    part += __shfl_xor(part, 1, 64);
    part += __shfl_xor(part, 2, 64);
    part += __shfl_xor(part, 4, 64);
    part += __shfl_xor(part, 8, 64);
    if (c == 0) {
        int rank = part;
        float4 a = *(const float4*)(res + gi * 8);
        float4 b = *(const float4*)(res + gi * 8 + 4);
        *(float4*)(rows + rank * 8)     = a;
        *(float4*)(rows + rank * 8 + 4) = b;
        // a = (score, class, cx, cy); b = (cz, dx, dy, dz)
        float cx = a.z, cy = a.w, cz = b.x, dx = b.y, dy = b.z, dz = b.w;
        soa[0 * N_DET + rank] = cx - dx * 0.5f;
        soa[1 * N_DET + rank] = cy - dy * 0.5f;
        soa[2 * N_DET + rank] = cz - dz * 0.5f;
        soa[3 * N_DET + rank] = cx + dx * 0.5f;
        soa[4 * N_DET + rank] = cy + dy * 0.5f;
        soa[5 * N_DET + rank] = cz + dz * 0.5f;
        soa[6 * N_DET + rank] = (dx * dy) * dz;   // np.prod order ((dx*dy)*dz)
    }
}

// K2: suppression rows, upper-triangle only (w >= i>>6), straight-line body
// (round-6 proven structure; no per-word branch). One wave per row i.
__global__ void k_sup(const float* __restrict__ soa, u64* __restrict__ Trm,
                      u64* __restrict__ A) {
    int lane = threadIdx.x & 63;
    int wave = threadIdx.x >> 6;
    int i = blockIdx.x * 4 + wave;
    float ilox = soa[0 * N_DET + i], iloy = soa[1 * N_DET + i], iloz = soa[2 * N_DET + i];
    float ihix = soa[3 * N_DET + i], ihiy = soa[4 * N_DET + i], ihiz = soa[5 * N_DET + i];
    float ivol = soa[6 * N_DET + i];
    u64 rowword = 0, rowOr = 0;
    for (int w = (i >> 6); w < NW; ++w) {
        int j = w * 64 + lane;
        float lox = soa[0 * N_DET + j], loy = soa[1 * N_DET + j], loz = soa[2 * N_DET + j];
        float hix = soa[3 * N_DET + j], hiy = soa[4 * N_DET + j], hiz = soa[5 * N_DET + j];
        float vol = soa[6 * N_DET + j];
        float ix = fminf(ihix, hix) - fmaxf(ilox, lox); ix = fmaxf(ix, 0.0f);
        float iy = fminf(ihiy, hiy) - fmaxf(iloy, loy); iy = fmaxf(iy, 0.0f);
        float iz = fminf(ihiz, hiz) - fmaxf(iloz, loz); iz = fmaxf(iz, 0.0f);
        float inter = (ix * iy) * iz;                 // ((x*y)*z) like np.prod
        float uni = ivol + vol - inter;               // (vol_i+vol_j)-inter
        float iou = inter / (uni + EPS);              // IEEE div
        bool sb = (iou > IOU_TR) && (j > i);
        u64 m = __ballot(sb);
        rowOr |= m;
        rowword = (lane == w) ? m : rowword;
    }
    if (rowOr) {                                      // wave-uniform branch
        Trm[(size_t)i * NW + lane] = rowword;         // coalesced 512B store
        if (lane == 0) atomicOr(&A[i >> 6], 1ull << (i & 63));
    }
}

// K3: valid ballots + sparse greedy scan (one 256-thread block) -> keep[].
#define FIDX(V, GB) { V = (unsigned)s_nlist[(GB) + (lane & 15)]; }

#define IS1(V, P, S) { unsigned si_ = __builtin_amdgcn_readlane((V), (S)); \
    P##S = Trm[(size_t)si_ * NW + lane]; }

#define IS16(V, P) IS1(V,P,0) IS1(V,P,1) IS1(V,P,2) IS1(V,P,3)   \
    IS1(V,P,4) IS1(V,P,5) IS1(V,P,6) IS1(V,P,7)                  \
    IS1(V,P,8) IS1(V,P,9) IS1(V,P,10) IS1(V,P,11)                \
    IS1(V,P,12) IS1(V,P,13) IS1(V,P,14) IS1(V,P,15)

#define PR1(V, P, S) { unsigned si_ = __builtin_amdgcn_readlane((V), (S)); \
    u64 awd_ = rl64(act, (int)(si_ >> 6));                                 \
    u64 bit_ = (awd_ >> (si_ & 63u)) & 1ull;                               \
    u64 m_ = (0ull - bit_) & (0ull - (u64)(si_ != 4095u));                 \
    act &= ~(P##S & m_); }

#define PR16(V, P) PR1(V,P,0) PR1(V,P,1) PR1(V,P,2) PR1(V,P,3)   \
    PR1(V,P,4) PR1(V,P,5) PR1(V,P,6) PR1(V,P,7)                  \
    PR1(V,P,8) PR1(V,P,9) PR1(V,P,10) PR1(V,P,11)                \
    PR1(V,P,12) PR1(V,P,13) PR1(V,P,14) PR1(V,P,15)

__global__ void __launch_bounds__(256, 1)
k_scan(const u64* __restrict__ Trm, const u64* __restrict__ A,
       const float* __restrict__ rows, u64* __restrict__ keep) {
    __shared__ u64 s_valid[NW];
    __shared__ unsigned short s_nlist[4224];
    const int tid = threadIdx.x;
    const int wv = tid >> 6;
    const int lane = tid & 63;

    for (int w = wv * 16; w < wv * 16 + 16; ++w) {
        float scw = rows[(w * 64 + lane) * 8];
        u64 m = __ballot(scw >= SCORE_TR);
        if (lane == 0) s_valid[w] = m;
    }
    __syncthreads();
    if (wv != 0) return;

    u64 act = s_valid[lane];
    u64 avA = A[lane];
    int pc = __popcll(avA);
    int inc = pc;
#pragma unroll
    for (int d = 1; d < 64; d <<= 1) {
        int t = __shfl_up(inc, d, 64);
        if (lane >= d) inc += t;
    }
    int exc = inc - pc;
    int nTotal = __shfl(inc, 63, 64);
    {   // emit this lane's nonempty-row indices (sorted globally)
        u64 m = avA; int o = exc;
        while (m) {
            int k = __builtin_ctzll(m); m &= m - 1;
            s_nlist[o++] = (unsigned short)(lane * 64 + k);
        }
    }
    int padded = (nTotal + 63) & ~63;
    for (int t = nTotal + lane; t < padded + 128; t += 64)
        s_nlist[t] = (unsigned short)4095;
    __threadfence_block();                 // wave-local LDS ordering

    if (padded > 0) {                      // padded is a multiple of 64
        u64 pa0,pa1,pa2,pa3,pa4,pa5,pa6,pa7,
            pa8,pa9,pa10,pa11,pa12,pa13,pa14,pa15;
        u64 pb0,pb1,pb2,pb3,pb4,pb5,pb6,pb7,
            pb8,pb9,pb10,pb11,pb12,pb13,pb14,pb15;
        unsigned iA0, iA1, iB0, iB1;
        FIDX(iA0, 0)  IS16(iA0, pa)
        FIDX(iB0, 16) IS16(iB0, pb)
        int g = 0;
        while (g < padded) {
            FIDX(iA1, g + 32)
            PR16(iA0, pa)                  // rows g..g+15
            IS16(iA1, pa)                  // issue g+32
            FIDX(iB1, g + 48)
            PR16(iB0, pb)                  // rows g+16..g+31
            IS16(iB1, pb)                  // issue g+48
            g += 32;
            if (g >= padded) break;
            FIDX(iA0, g + 32)
            PR16(iA1, pa)
            IS16(iA0, pa)
            FIDX(iB0, g + 48)
            PR16(iB1, pb)
            IS16(iB0, pb)
            g += 32;
        }
    }
    keep[lane] = act;                      // final act == keep mask
}

// K4: gated output, 16 blocks x 256 threads, coalesced.
__global__ void k_out(const float* __restrict__ rows,
                      const u64* __restrict__ keep,
                      float* __restrict__ out) {
    int i = blockIdx.x * 256 + threadIdx.x;
    bool kp = (keep[i >> 6] >> (i & 63)) & 1ull;
    float4 a = kp ? ((const float4*)rows)[i * 2]     : make_float4(0.f, 0.f, 0.f, 0.f);
    float4 b = kp ? ((const float4*)rows)[i * 2 + 1] : make_float4(0.f, 0.f, 0.f, 0.f);
    ((float4*)out)[i * 2]     = a;
    ((float4*)out)[i * 2 + 1] = b;
}

extern "C" void kernel_launch(void* const* d_in, const int* in_sizes, int n_in,
                              void* d_out, int out_size, void* d_ws, size_t ws_size,
                              hipStream_t stream) {
    const float* res = (const float*)d_in[0];
    float* out = (float*)d_out;

    float* rows = (float*)d_ws;                       // 32768 f32
    float* soa  = rows + N_DET * 8;                   // 28672 f32
    u64* A      = (u64*)(soa + 7 * N_DET);            // 64 u64
    u64* keep   = A + NW;                             // 64 u64
    u64* Trm    = keep + NW;                          // 4096*64 u64 (row-major)

    k_sort<<<N_DET / 16, 256, 0, stream>>>(res, rows, soa, A);
    k_sup <<<N_DET / 4, 256, 0, stream>>>(soa, Trm, A);
    k_scan<<<1, 256, 0, stream>>>(Trm, A, rows, keep);
    k_out <<<16, 256, 0, stream>>>(rows, keep, out);
}